// Round 24
// baseline (2553.785 us; speedup 1.0000x reference)
//
#include <hip/hip_runtime.h>
#include <hip/hip_bf16.h>
#include <math.h>

typedef __hip_bfloat16 bf16;
typedef __attribute__((ext_vector_type(8))) short s8v;
typedef __attribute__((ext_vector_type(4))) short s4v;
typedef __attribute__((ext_vector_type(4))) float f4v;

#define B_   64
#define N_   512
#define L_   12
#define H_   12
#define RNN  64
#define MEMN 20
#define MEMD 64
#define DD   128
#define NB   32768          // N_*B_ ; r = b*512 + n (b-major)

// Channel layout (permuted): c in [0,HD) = h-channels; c in [HD,HD+MC) = misc
// (enc: HD=64, MC=1 (x); dec: HD=128, MC=6 (go,tt0..4)); c >= HD+MC pad (W=0).

// ---------- global->LDS 16B DMA ----------
__device__ inline void glds16(const bf16* g, bf16* l) {
  __builtin_amdgcn_global_load_lds((const __attribute__((address_space(1))) void*)g,
                                   (__attribute__((address_space(3))) void*)l, 16, 0, 0);
}

// ---------- XCD-aware bijective swizzle (2-D grid) ----------
__device__ inline int2 xcd_swz() {
  int lid = blockIdx.x + blockIdx.y * gridDim.x;
  int chunk = (gridDim.x * gridDim.y) >> 3;
  int swz = (lid & 7) * chunk + (lid >> 3);
  int bx = swz / gridDim.y;
  int by = swz - bx * gridDim.y;
  return make_int2(bx, by);
}

// =================== MFMA GEMM 1: graph mix (R4 structure + XCD swizzle) =======
template<int C_CH, int CP>
__global__ __launch_bounds__(256) void gemm_mix(
    const bf16* __restrict__ Sb, const bf16* __restrict__ XT, bf16* __restrict__ Yb) {
  const int NCOLS = 64 * C_CH;
  __shared__ bf16 As[128 * 32];
  __shared__ bf16 Bs[128 * 32];
  const int tid = threadIdx.x, lane = tid & 63, wid = tid >> 6;
  const int wr = wid >> 1, wc = wid & 1;
  int2 sz = xcd_swz();
  const int bn = sz.x * 128, bm = sz.y * 128;
  const int r_in = lane >> 2, dslot = lane & 3;
  f4v acc[4][4] = {};
  for (int k0 = 0; k0 < 512; k0 += 32) {
#pragma unroll
    for (int h = 0; h < 2; h++) {
      int ci = wid + h * 4;
      int row = ci * 16 + r_in;
      int ss = dslot ^ ((row >> 1) & 3);
      glds16(Sb + (size_t)(bm + row) * 512 + k0 + ss * 8, As + ci * 512);
      glds16(XT + (size_t)(bn + row) * 512 + k0 + ss * 8, Bs + ci * 512);
    }
    asm volatile("s_waitcnt vmcnt(0)" ::: "memory");
    __syncthreads();
    s8v a[4], bb[4];
#pragma unroll
    for (int m = 0; m < 4; m++) {
      int row = wr * 64 + m * 16 + (lane & 15);
      int slot = (lane >> 4) ^ ((row >> 1) & 3);
      a[m] = *(const s8v*)(As + row * 32 + slot * 8);
    }
#pragma unroll
    for (int n = 0; n < 4; n++) {
      int col = wc * 64 + n * 16 + (lane & 15);
      int slot = (lane >> 4) ^ ((col >> 1) & 3);
      bb[n] = *(const s8v*)(Bs + col * 32 + slot * 8);
    }
#pragma unroll
    for (int m = 0; m < 4; m++)
#pragma unroll
      for (int n = 0; n < 4; n++)
        acc[m][n] = __builtin_amdgcn_mfma_f32_16x16x32_bf16(a[m], bb[n], acc[m][n], 0, 0, 0);
    __syncthreads();
  }
#pragma unroll
  for (int m = 0; m < 4; m++) {
#pragma unroll
    for (int rg = 0; rg < 4; rg++) {
      int row = bm + wr * 64 + m * 16 + (lane >> 4) * 4 + rg;
      int s = row >> 9, nn = row & 511;
      size_t obase = (size_t)s * NB * CP;
#pragma unroll
      for (int n = 0; n < 4; n++) {
        int col = bn + wc * 64 + n * 16 + (lane & 15);
        if (col < NCOLS) {
          int b2 = col / C_CH, c = col - b2 * C_CH;
          Yb[obase + (size_t)(b2 * 512 + nn) * CP + c] = __float2bfloat16(acc[m][n][rg]);
        }
      }
    }
  }
}

// =================== MFMA GEMM 2: projection (M=OPAD, N=32, grid 1024) =========
// Block: 4 waves, wave wo owns rows [wo*OPAD/4,...) x all 32 cols.
// EPI 0 (gates): o<hd -> zh=sigmoid*HT -> XTo/XCo; o>=hd -> RG bf16.
// EPI 1 (upd):   hn = rg*HT+(1-rg)*tanh -> HT + XTo/XCo; + misc x[tnext] -> 4 bufs.
// EPI 2:         EPI1 + fused GO/out; GO + tt[tnext] -> 4 bufs.
template<int CP, int OPAD, int EPI, int CCH>
__global__ __launch_bounds__(256) void gemm_proj(
    const bf16* __restrict__ WT, const bf16* __restrict__ XCin,
    const bf16* __restrict__ Yb, const float* __restrict__ bias,
    bf16* __restrict__ RG, float* __restrict__ HT, int hd,
    const float* __restrict__ pW, const float* __restrict__ pb,
    float* __restrict__ outp, bf16* __restrict__ XTo, bf16* __restrict__ XCo,
    bf16* __restrict__ XTa, bf16* __restrict__ XCa, int t,
    const float* __restrict__ msrc, int tnext) {
  constexpr int MPW = OPAD / 4;          // rows per wave
  constexpr int MF  = MPW / 16;          // m-frags per wave
  __shared__ bf16 As[OPAD * 32];
  __shared__ bf16 Bs[32 * 32];
  __shared__ float red2[16 * 32];
  __shared__ float pws[128];
  const int tid = threadIdx.x, lane = tid & 63, wo = tid >> 6;
  int swb = (blockIdx.x & 7) * (gridDim.x >> 3) + (blockIdx.x >> 3);
  const int r0 = swb * 32;
  const int r_in = lane >> 2, dslot = lane & 3;

  if (EPI == 2 && tid < 128) pws[tid] = pW[tid];

  f4v acc[MF][2] = {};
#pragma unroll
  for (int seg = 0; seg < 5; seg++) {
    const bf16* Bbase = (seg == 0) ? XCin : (Yb + (size_t)(seg - 1) * NB * CP);
    const bf16* Abase = WT + (size_t)seg * OPAD * CP;
    for (int k0 = 0; k0 < CP; k0 += 32) {
      for (int ci = wo; ci < OPAD / 16; ci += 4) {
        int row = ci * 16 + r_in;
        int ss = dslot ^ ((row >> 1) & 3);
        glds16(Abase + (size_t)row * CP + k0 + ss * 8, As + ci * 512);
      }
      if (wo < 2) {
        int row = wo * 16 + r_in;
        int ss = dslot ^ ((row >> 1) & 3);
        glds16(Bbase + (size_t)(r0 + row) * CP + k0 + ss * 8, Bs + wo * 512);
      }
      asm volatile("s_waitcnt vmcnt(0)" ::: "memory");
      __syncthreads();
      s8v a[MF], bb[2];
#pragma unroll
      for (int m = 0; m < MF; m++) {
        int row = wo * MPW + m * 16 + (lane & 15);
        int slot = (lane >> 4) ^ ((row >> 1) & 3);
        a[m] = *(const s8v*)(As + row * 32 + slot * 8);
      }
#pragma unroll
      for (int n = 0; n < 2; n++) {
        int col = n * 16 + (lane & 15);
        int slot = (lane >> 4) ^ ((col >> 1) & 3);
        bb[n] = *(const s8v*)(Bs + col * 32 + slot * 8);
      }
#pragma unroll
      for (int m = 0; m < MF; m++)
#pragma unroll
        for (int n = 0; n < 2; n++)
          acc[m][n] = __builtin_amdgcn_mfma_f32_16x16x32_bf16(a[m], bb[n], acc[m][n], 0, 0, 0);
      __syncthreads();
    }
  }

#pragma unroll
  for (int m = 0; m < MF; m++) {
#pragma unroll
    for (int n = 0; n < 2; n++) {
      int r = r0 + n * 16 + (lane & 15);
      int b2 = r >> 9, nn = r & 511;
      int ch0 = wo * MPW + m * 16 + (lane >> 4) * 4;
      if (EPI == 0) {
        if (ch0 < hd) {
          bf16 z4[4];
#pragma unroll
          for (int rg = 0; rg < 4; rg++) {
            int o = ch0 + rg;
            float sg = 1.f / (1.f + expf(-(acc[m][n][rg] + bias[o])));
            float hold = HT[(size_t)o * NB + r];
            z4[rg] = __float2bfloat16(sg * hold);
            XTo[((size_t)b2 * CCH + o) * 512 + nn] = z4[rg];
          }
          *(s4v*)(XCo + (size_t)r * CP + ch0) = *(const s4v*)z4;
        } else {
#pragma unroll
          for (int rg = 0; rg < 4; rg++) {
            int o = ch0 + rg;
            float sg = 1.f / (1.f + expf(-(acc[m][n][rg] + bias[o])));
            RG[(size_t)(o - hd) * NB + r] = __float2bfloat16(sg);
          }
        }
      } else {
        if (ch0 < hd) {
          bf16 h4[4];
#pragma unroll
          for (int rg = 0; rg < 4; rg++) {
            int o = ch0 + rg;
            float hc = tanhf(acc[m][n][rg] + bias[o]);
            float rgt = __bfloat162float(RG[(size_t)o * NB + r]);
            float* hp = HT + (size_t)o * NB + r;
            float hn = rgt * (*hp) + (1.f - rgt) * hc;
            *hp = hn;
            h4[rg] = __float2bfloat16(hn);
            XTo[((size_t)b2 * CCH + o) * 512 + nn] = h4[rg];
            acc[m][n][rg] = hn;
          }
          *(s4v*)(XCo + (size_t)r * CP + ch0) = *(const s4v*)h4;
        }
      }
    }
  }

  // ---- EPI 1: fold next-step x misc channel into all 4 input buffers ----
  if (EPI == 1 && msrc != nullptr && tnext < L_ && tid < 32) {
    int r = r0 + tid;
    int b2 = r >> 9, nn = r & 511;
    bf16 v = __float2bfloat16(msrc[b2 * 6144 + nn * 12 + tnext]);
    XTo[((size_t)b2 * CCH + hd) * 512 + nn] = v;
    XCo[(size_t)r * CP + hd] = v;
    XTa[((size_t)b2 * CCH + hd) * 512 + nn] = v;
    XCa[(size_t)r * CP + hd] = v;
  }

  if (EPI == 2) {
    __syncthreads();
#pragma unroll
    for (int n = 0; n < 2; n++) {
      int r_local = n * 16 + (lane & 15);
      float ps = 0.f;
#pragma unroll
      for (int m = 0; m < MF; m++)
#pragma unroll
        for (int rg = 0; rg < 4; rg++) {
          int o = wo * MPW + m * 16 + (lane >> 4) * 4 + rg;
          ps += acc[m][n][rg] * pws[o];
        }
      red2[(wo * 4 + (lane >> 4)) * 32 + r_local] = ps;
    }
    __syncthreads();
    if (tid < 32) {
      float v = pb[0];
#pragma unroll
      for (int s2 = 0; s2 < 16; s2++) v += red2[s2 * 32 + tid];
      int r = r0 + tid;
      int b2 = r >> 9, nn = r & 511;
      outp[b2 * 6144 + nn * 12 + t] = v;
      bf16 gb = __float2bfloat16(v);
      XTo[((size_t)b2 * CCH + hd) * 512 + nn] = gb;
      XCo[(size_t)r * CP + hd] = gb;
      XTa[((size_t)b2 * CCH + hd) * 512 + nn] = gb;
      XCa[(size_t)r * CP + hd] = gb;
      // fold next-step tt channels into all 4 buffers
      if (msrc != nullptr && tnext < H_) {
#pragma unroll
        for (int ch = 0; ch < 5; ch++) {
          bf16 tv = __float2bfloat16(msrc[b2 * 60 + ch * 12 + tnext]);
          int c = hd + 1 + ch;
          XTo[((size_t)b2 * CCH + c) * 512 + nn] = tv;
          XCo[(size_t)r * CP + c] = tv;
          XTa[((size_t)b2 * CCH + c) * 512 + nn] = tv;
          XCa[(size_t)r * CP + c] = tv;
        }
      }
    }
  }
}

// =================== MFMA Chebyshev: O = 2*A@B - I ===========
__global__ __launch_bounds__(256) void gemm_cheb(
    const bf16* __restrict__ A, const bf16* __restrict__ BT, bf16* __restrict__ O) {
  __shared__ bf16 As[128 * 32];
  __shared__ bf16 Bs[128 * 32];
  const int tid = threadIdx.x, lane = tid & 63, wid = tid >> 6;
  const int wr = wid >> 1, wc = wid & 1;
  const int bm = blockIdx.y * 128, bn = blockIdx.x * 128;
  const int r_in = lane >> 2, dslot = lane & 3;
  f4v acc[4][4] = {};
  for (int k0 = 0; k0 < 512; k0 += 32) {
#pragma unroll
    for (int h = 0; h < 2; h++) {
      int ci = wid + h * 4;
      int row = ci * 16 + r_in;
      int ss = dslot ^ ((row >> 1) & 3);
      glds16(A + (size_t)(bm + row) * 512 + k0 + ss * 8, As + ci * 512);
      glds16(BT + (size_t)(bn + row) * 512 + k0 + ss * 8, Bs + ci * 512);
    }
    asm volatile("s_waitcnt vmcnt(0)" ::: "memory");
    __syncthreads();
    s8v a[4], bb[4];
#pragma unroll
    for (int m = 0; m < 4; m++) {
      int row = wr * 64 + m * 16 + (lane & 15);
      int slot = (lane >> 4) ^ ((row >> 1) & 3);
      a[m] = *(const s8v*)(As + row * 32 + slot * 8);
    }
#pragma unroll
    for (int n = 0; n < 4; n++) {
      int col = wc * 64 + n * 16 + (lane & 15);
      int slot = (lane >> 4) ^ ((col >> 1) & 3);
      bb[n] = *(const s8v*)(Bs + col * 32 + slot * 8);
    }
#pragma unroll
    for (int m = 0; m < 4; m++)
#pragma unroll
      for (int n = 0; n < 4; n++)
        acc[m][n] = __builtin_amdgcn_mfma_f32_16x16x32_bf16(a[m], bb[n], acc[m][n], 0, 0, 0);
    __syncthreads();
  }
#pragma unroll
  for (int m = 0; m < 4; m++) {
#pragma unroll
    for (int rg = 0; rg < 4; rg++) {
      int row = bm + wr * 64 + m * 16 + (lane >> 4) * 4 + rg;
#pragma unroll
      for (int n = 0; n < 4; n++) {
        int col = bn + wc * 64 + n * 16 + (lane & 15);
        float v = 2.f * acc[m][n][rg] - (row == col ? 1.f : 0.f);
        O[(size_t)row * 512 + col] = __float2bfloat16(v);
      }
    }
  }
}

// ---------------- small kernels ----------------
__global__ void fill_zero4(float4* p, int n) {
  for (int i = blockIdx.x * 256 + threadIdx.x; i < n; i += gridDim.x * 256)
    p[i] = make_float4(0.f, 0.f, 0.f, 0.f);
}

__global__ void compute_e(const float* __restrict__ We1, const float* __restrict__ We2,
                          const float* __restrict__ Mem, float* __restrict__ e1,
                          float* __restrict__ e2) {
  int idx = blockIdx.x * 256 + threadIdx.x;
  if (idx >= N_ * MEMD) return;
  int n = idx >> 6, d = idx & 63;
  float s1 = 0.f, s2 = 0.f;
  for (int k = 0; k < MEMN; k++) {
    float m = Mem[k * MEMD + d];
    s1 += We1[n * MEMN + k] * m;
    s2 += We2[n * MEMN + k] * m;
  }
  e1[idx] = s1; e2[idx] = s2;
}

__global__ void compute_wqm(const float* __restrict__ Wq, const float* __restrict__ Mem,
                            float* __restrict__ WqM) {
  int idx = blockIdx.x * 256 + threadIdx.x;
  if (idx >= RNN * MEMN) return;
  int c = idx / MEMN, j = idx - c * MEMN;
  float s = 0.f;
  for (int d = 0; d < MEMD; d++) s += Wq[c * MEMD + d] * Mem[j * MEMD + d];
  WqM[idx] = s;
}

__global__ void scores_relu(const float* __restrict__ e1, const float* __restrict__ e2,
                            float* __restrict__ S) {
  int idx = blockIdx.x * 256 + threadIdx.x;
  if (idx >= N_ * N_) return;
  int n = idx >> 9, m = idx & 511;
  float s = 0.f;
  for (int k = 0; k < MEMD; k++) s += e1[n * MEMD + k] * e2[m * MEMD + k];
  S[idx] = s > 0.f ? s : 0.f;
}

__global__ __launch_bounds__(256)
void row_softmax(const float* __restrict__ S, float* __restrict__ G) {
  int r = blockIdx.x;
  __shared__ float red[256];
  float m = -1e30f;
  for (int j = threadIdx.x; j < N_; j += 256) m = fmaxf(m, S[r * N_ + j]);
  red[threadIdx.x] = m; __syncthreads();
  for (int s = 128; s > 0; s >>= 1) {
    if (threadIdx.x < s) red[threadIdx.x] = fmaxf(red[threadIdx.x], red[threadIdx.x + s]);
    __syncthreads();
  }
  m = red[0]; __syncthreads();
  float sum = 0.f;
  for (int j = threadIdx.x; j < N_; j += 256) sum += expf(S[r * N_ + j] - m);
  red[threadIdx.x] = sum; __syncthreads();
  for (int s = 128; s > 0; s >>= 1) {
    if (threadIdx.x < s) red[threadIdx.x] += red[threadIdx.x + s];
    __syncthreads();
  }
  float inv = 1.f / red[0];
  for (int j = threadIdx.x; j < N_; j += 256)
    G[r * N_ + j] = expf(S[r * N_ + j] - m) * inv;
}

__global__ void trans_f32(const float* __restrict__ in, float* __restrict__ outT) {
  __shared__ float t[32][33];
  int bx = blockIdx.x * 32, by = blockIdx.y * 32;
  int x = threadIdx.x, y = threadIdx.y;           // block (32,8)
  for (int i = 0; i < 32; i += 8) t[y + i][x] = in[(by + y + i) * 512 + bx + x];
  __syncthreads();
  for (int i = 0; i < 32; i += 8) outT[(bx + y + i) * 512 + by + x] = t[x][y + i];
}

__global__ void trans_to_bf16(const float* __restrict__ in, bf16* __restrict__ outN,
                              bf16* __restrict__ outT) {
  __shared__ float t[32][33];
  int bx = blockIdx.x * 32, by = blockIdx.y * 32;
  int x = threadIdx.x, y = threadIdx.y;           // block (32,8)
  for (int i = 0; i < 32; i += 8) {
    float v = in[(by + y + i) * 512 + bx + x];
    t[y + i][x] = v;
    outN[(by + y + i) * 512 + bx + x] = __float2bfloat16(v);
  }
  __syncthreads();
  for (int i = 0; i < 32; i += 8)
    outT[(bx + y + i) * 512 + by + x] = __float2bfloat16(t[x][y + i]);
}

// WT[seg][Opad][CP]; permuted channels: c<HD -> ref row MC+c; HD<=c<HD+MC -> ref c-HD.
__global__ void prep_wt(const float* __restrict__ W, bf16* __restrict__ WT,
                        int C, int O, int Opad, int CP, int HD, int MC) {
  int idx = blockIdx.x * 256 + threadIdx.x;
  int tot = 5 * Opad * CP;
  if (idx >= tot) return;
  int seg = idx / (Opad * CP);
  int rem = idx - seg * (Opad * CP);
  int o = rem / CP, c = rem - (rem / CP) * CP;
  float v = 0.f;
  int srcc = -1;
  if (c < HD) srcc = MC + c;
  else if (c < HD + MC) srcc = c - HD;
  if (srcc >= 0 && o < O) {
    const int blkmap[5] = {0, 1, 2, 4, 5};
    int blk = blkmap[seg];
    v = W[(blk * C + srcc) * O + o];
    if (seg == 0) v += W[(3 * C + srcc) * O + o];
  }
  WT[idx] = __float2bfloat16(v);
}

// ---- t=0 misc fills ----
__global__ void fill_misc_enc(bf16* __restrict__ XTh, bf16* __restrict__ XTz,
                              bf16* __restrict__ XCh, bf16* __restrict__ XCz,
                              const float* __restrict__ x, int t) {
  int r = blockIdx.x * 256 + threadIdx.x;
  if (r >= NB) return;
  int b = r >> 9, n = r & 511;
  bf16 v = __float2bfloat16(x[b * 6144 + n * 12 + t]);
  XTh[((size_t)b * 65 + 64) * 512 + n] = v;
  XTz[((size_t)b * 65 + 64) * 512 + n] = v;
  XCh[(size_t)r * 96 + 64] = v;
  XCz[(size_t)r * 96 + 64] = v;
}

__global__ void fill_misc_dec(bf16* __restrict__ XTh, bf16* __restrict__ XTz,
                              bf16* __restrict__ XCh, bf16* __restrict__ XCz,
                              const float* __restrict__ tt, int t, int writego) {
  int idx = blockIdx.x * 256 + threadIdx.x;
  if (idx >= NB * 6) return;
  int ch = idx >> 15, r = idx & (NB - 1);
  int b = r >> 9, n = r & 511;
  bf16 v;
  int c;
  if (ch < 5) { v = __float2bfloat16(tt[b * 60 + ch * 12 + t]); c = 129 + ch; }
  else { if (!writego) return; v = __float2bfloat16(0.f); c = 128; }
  XTh[((size_t)b * 134 + c) * 512 + n] = v;
  XTz[((size_t)b * 134 + c) * 512 + n] = v;
  XCh[(size_t)r * 160 + c] = v;
  XCz[(size_t)r * 160 + c] = v;
}

// ---- attention: seeds dec gates input ----
__global__ __launch_bounds__(128) void attention2(
    const float* __restrict__ HbT, const float* __restrict__ WqM,
    const float* __restrict__ Mem, float* __restrict__ HdT,
    bf16* __restrict__ XTh, bf16* __restrict__ XCh) {
  __shared__ float h[64][128];
  __shared__ float wqm[64][20];
  __shared__ float mem[20][64];
  const int tid = threadIdx.x, r0 = blockIdx.x * 128;
  const int r = r0 + tid, b = r >> 9, n = r & 511;
  for (int e = tid; e < 64 * 128; e += 128) {
    int c = e >> 7, j = e & 127;
    h[c][j] = HbT[(size_t)c * NB + r0 + j];
  }
  for (int e = tid; e < 1280; e += 128) {
    wqm[e / 20][e % 20] = WqM[e];
    mem[e >> 6][e & 63] = Mem[e];
  }
  __syncthreads();
  float s[20];
#pragma unroll
  for (int j = 0; j < 20; j++) s[j] = 0.f;
  for (int c = 0; c < 64; c++) {
    float hv = h[c][tid];
#pragma unroll
    for (int j = 0; j < 20; j++) s[j] += hv * wqm[c][j];
  }
  float mx = s[0];
#pragma unroll
  for (int j = 1; j < 20; j++) mx = fmaxf(mx, s[j]);
  float sum = 0.f;
#pragma unroll
  for (int j = 0; j < 20; j++) { s[j] = expf(s[j] - mx); sum += s[j]; }
  float inv = 1.f / sum;
#pragma unroll
  for (int j = 0; j < 20; j++) s[j] *= inv;
  for (int d = 0; d < 64; d++) {
    float ha = 0.f;
#pragma unroll
    for (int j = 0; j < 20; j++) ha += s[j] * mem[j][d];
    float hv = h[d][tid];
    HdT[(size_t)d * NB + r] = hv;
    HdT[(size_t)(64 + d) * NB + r] = ha;
    bf16 hb = __float2bfloat16(hv), ab = __float2bfloat16(ha);
    XTh[((size_t)b * 134 + d) * 512 + n] = hb;
    XTh[((size_t)b * 134 + 64 + d) * 512 + n] = ab;
    XCh[(size_t)r * 160 + d] = hb;
    XCh[(size_t)r * 160 + 64 + d] = ab;
  }
}

// ---------------- host ----------------
extern "C" void kernel_launch(void* const* d_in, const int* in_sizes, int n_in,
                              void* d_out, int out_size, void* d_ws, size_t ws_size,
                              hipStream_t stream) {
  const float* x   = (const float*)d_in[0];
  const float* tt  = (const float*)d_in[3];
  const float* Mem = (const float*)d_in[5];
  const float* Wq  = (const float*)d_in[6];
  const float* We1 = (const float*)d_in[7];
  const float* We2 = (const float*)d_in[8];
  const float* egW = (const float*)d_in[9];
  const float* egb = (const float*)d_in[10];
  const float* euW = (const float*)d_in[11];
  const float* eub = (const float*)d_in[12];
  const float* dgW = (const float*)d_in[13];
  const float* dgb = (const float*)d_in[14];
  const float* duW = (const float*)d_in[15];
  const float* dub = (const float*)d_in[16];
  const float* pW  = (const float*)d_in[17];
  const float* pb  = (const float*)d_in[18];
  float* out = (float*)d_out;

  char* ws = (char*)d_ws;
  size_t off = 0;
  auto alloc = [&](size_t bytes) { char* p = ws + off; off += (bytes + 255) & ~(size_t)255; return p; };
  // ---- zeroed-at-launch-start region ----
  bf16* XTh   = (bf16*)alloc((size_t)8576 * 512 * 2);
  bf16* XCh   = (bf16*)alloc((size_t)NB * 160 * 2);
  float* HbT  = (float*)alloc((size_t)RNN * NB * 4);
  size_t zero_bytes = off;
  // ---- rest ----
  bf16* XTz   = (bf16*)alloc((size_t)8576 * 512 * 2);
  bf16* XCz   = (bf16*)alloc((size_t)NB * 160 * 2);
  bf16* Ybuf  = (bf16*)alloc((size_t)4 * NB * 160 * 2);
  bf16* RG    = (bf16*)alloc((size_t)DD * NB * 2);
  bf16* WTeg  = (bf16*)alloc((size_t)5 * 128 * 96 * 2);
  bf16* WTeu  = (bf16*)alloc((size_t)5 * 64 * 96 * 2);
  bf16* WTdg  = (bf16*)alloc((size_t)5 * 256 * 160 * 2);
  bf16* WTdu  = (bf16*)alloc((size_t)5 * 128 * 160 * 2);
  bf16* Sb    = (bf16*)alloc((size_t)4 * 512 * 512 * 2);
  bf16* g1T   = (bf16*)alloc((size_t)512 * 512 * 2);
  bf16* g2T   = (bf16*)alloc((size_t)512 * 512 * 2);
  float* HdT  = (float*)alloc((size_t)DD * NB * 4);
  float* WqM  = (float*)alloc((size_t)RNN * MEMN * 4);
  float* e1   = (float*)alloc((size_t)N_ * MEMD * 4);
  float* e2   = (float*)alloc((size_t)N_ * MEMD * 4);
  float* S    = (float*)alloc((size_t)N_ * N_ * 4);
  float* ST   = (float*)alloc((size_t)N_ * N_ * 4);
  float* g1f  = (float*)alloc((size_t)N_ * N_ * 4);
  float* g2f  = (float*)alloc((size_t)N_ * N_ * 4);

  auto blk = [](long n) { return dim3((unsigned)((n + 255) / 256)); };

  // ---- phase 0 ----
  fill_zero4<<<2048, 256, 0, stream>>>((float4*)ws, (int)(zero_bytes / 16));
  compute_e<<<blk(N_ * MEMD), 256, 0, stream>>>(We1, We2, Mem, e1, e2);
  compute_wqm<<<blk(RNN * MEMN), 256, 0, stream>>>(Wq, Mem, WqM);
  scores_relu<<<blk(N_ * N_), 256, 0, stream>>>(e1, e2, S);
  trans_f32<<<dim3(16, 16), dim3(32, 8), 0, stream>>>(S, ST);
  row_softmax<<<N_, 256, 0, stream>>>(S, g1f);
  row_softmax<<<N_, 256, 0, stream>>>(ST, g2f);
  trans_to_bf16<<<dim3(16, 16), dim3(32, 8), 0, stream>>>(g1f, Sb + 0 * 262144, g1T);
  trans_to_bf16<<<dim3(16, 16), dim3(32, 8), 0, stream>>>(g2f, Sb + 2 * 262144, g2T);
  gemm_cheb<<<dim3(4, 4), 256, 0, stream>>>(Sb + 0 * 262144, g1T, Sb + 1 * 262144);
  gemm_cheb<<<dim3(4, 4), 256, 0, stream>>>(Sb + 2 * 262144, g2T, Sb + 3 * 262144);
  prep_wt<<<blk(5 * 128 * 96), 256, 0, stream>>>(egW, WTeg, 65, 128, 128, 96, 64, 1);
  prep_wt<<<blk(5 * 64 * 96), 256, 0, stream>>>(euW, WTeu, 65, 64, 64, 96, 64, 1);
  prep_wt<<<blk(5 * 256 * 160), 256, 0, stream>>>(dgW, WTdg, 134, 256, 256, 160, 128, 6);
  prep_wt<<<blk(5 * 128 * 160), 256, 0, stream>>>(duW, WTdu, 134, 128, 128, 160, 128, 6);

  // ---- encoder ----
  fill_misc_enc<<<blk(NB), 256, 0, stream>>>(XTh, XTz, XCh, XCz, x, 0);
  for (int t = 0; t < L_; t++) {
    gemm_mix<65, 96><<<dim3(33, 16), 256, 0, stream>>>(Sb, XTh, Ybuf);
    gemm_proj<96, 128, 0, 65><<<1024, 256, 0, stream>>>(
        WTeg, XCh, Ybuf, egb, RG, HbT, RNN, nullptr, nullptr, nullptr,
        XTz, XCz, nullptr, nullptr, 0, nullptr, 99);
    gemm_mix<65, 96><<<dim3(33, 16), 256, 0, stream>>>(Sb, XTz, Ybuf);
    gemm_proj<96, 64, 1, 65><<<1024, 256, 0, stream>>>(
        WTeu, XCz, Ybuf, eub, RG, HbT, RNN, nullptr, nullptr, nullptr,
        XTh, XCh, XTz, XCz, 0, x, t + 1);
  }

  // ---- attention -> HdT + seed dec gates input ----
  attention2<<<dim3(256), 128, 0, stream>>>(HbT, WqM, Mem, HdT, XTh, XCh);

  // ---- decoder ----
  fill_misc_dec<<<blk((long)NB * 6), 256, 0, stream>>>(XTh, XTz, XCh, XCz, tt, 0, 1);
  for (int t = 0; t < H_; t++) {
    gemm_mix<134, 160><<<dim3(67, 16), 256, 0, stream>>>(Sb, XTh, Ybuf);
    gemm_proj<160, 256, 0, 134><<<1024, 256, 0, stream>>>(
        WTdg, XCh, Ybuf, dgb, RG, HdT, DD, nullptr, nullptr, nullptr,
        XTz, XCz, nullptr, nullptr, 0, nullptr, 99);
    gemm_mix<134, 160><<<dim3(67, 16), 256, 0, stream>>>(Sb, XTz, Ybuf);
    gemm_proj<160, 128, 2, 134><<<1024, 256, 0, stream>>>(
        WTdu, XCz, Ybuf, dub, RG, HdT, DD, pW, pb, out,
        XTh, XCh, XTz, XCz, t, tt, t + 1);
  }
}

// Round 25
// 2549.302 us; speedup vs baseline: 1.0018x; 1.0018x over previous
//
#include <hip/hip_runtime.h>
#include <hip/hip_bf16.h>
#include <math.h>

typedef __hip_bfloat16 bf16;
typedef __attribute__((ext_vector_type(8))) short s8v;
typedef __attribute__((ext_vector_type(4))) short s4v;
typedef __attribute__((ext_vector_type(4))) float f4v;

#define B_   64
#define N_   512
#define L_   12
#define H_   12
#define RNN  64
#define MEMN 20
#define MEMD 64
#define DD   128
#define NB   32768          // N_*B_ ; r = b*512 + n (b-major)

// Channel layout (permuted): c in [0,HD) = h-channels; c in [HD,HD+MC) = misc
// (enc: HD=64, MC=1 (x); dec: HD=128, MC=6 (go,tt0..4)); c >= HD+MC pad (W=0).

// ---------- global->LDS 16B DMA ----------
__device__ inline void glds16(const bf16* g, bf16* l) {
  __builtin_amdgcn_global_load_lds((const __attribute__((address_space(1))) void*)g,
                                   (__attribute__((address_space(3))) void*)l, 16, 0, 0);
}

// ---------- XCD-aware bijective swizzle (2-D grid) ----------
__device__ inline int2 xcd_swz() {
  int lid = blockIdx.x + blockIdx.y * gridDim.x;
  int chunk = (gridDim.x * gridDim.y) >> 3;
  int swz = (lid & 7) * chunk + (lid >> 3);
  int bx = swz / gridDim.y;
  int by = swz - bx * gridDim.y;
  return make_int2(bx, by);
}

// =================== MFMA GEMM 1: graph mix (R4 structure + XCD swizzle) =======
template<int C_CH, int CP>
__global__ __launch_bounds__(256) void gemm_mix(
    const bf16* __restrict__ Sb, const bf16* __restrict__ XT, bf16* __restrict__ Yb) {
  const int NCOLS = 64 * C_CH;
  __shared__ bf16 As[128 * 32];
  __shared__ bf16 Bs[128 * 32];
  const int tid = threadIdx.x, lane = tid & 63, wid = tid >> 6;
  const int wr = wid >> 1, wc = wid & 1;
  int2 sz = xcd_swz();
  const int bn = sz.x * 128, bm = sz.y * 128;
  const int r_in = lane >> 2, dslot = lane & 3;
  f4v acc[4][4] = {};
  for (int k0 = 0; k0 < 512; k0 += 32) {
#pragma unroll
    for (int h = 0; h < 2; h++) {
      int ci = wid + h * 4;
      int row = ci * 16 + r_in;
      int ss = dslot ^ ((row >> 1) & 3);
      glds16(Sb + (size_t)(bm + row) * 512 + k0 + ss * 8, As + ci * 512);
      glds16(XT + (size_t)(bn + row) * 512 + k0 + ss * 8, Bs + ci * 512);
    }
    asm volatile("s_waitcnt vmcnt(0)" ::: "memory");
    __syncthreads();
    s8v a[4], bb[4];
#pragma unroll
    for (int m = 0; m < 4; m++) {
      int row = wr * 64 + m * 16 + (lane & 15);
      int slot = (lane >> 4) ^ ((row >> 1) & 3);
      a[m] = *(const s8v*)(As + row * 32 + slot * 8);
    }
#pragma unroll
    for (int n = 0; n < 4; n++) {
      int col = wc * 64 + n * 16 + (lane & 15);
      int slot = (lane >> 4) ^ ((col >> 1) & 3);
      bb[n] = *(const s8v*)(Bs + col * 32 + slot * 8);
    }
#pragma unroll
    for (int m = 0; m < 4; m++)
#pragma unroll
      for (int n = 0; n < 4; n++)
        acc[m][n] = __builtin_amdgcn_mfma_f32_16x16x32_bf16(a[m], bb[n], acc[m][n], 0, 0, 0);
    __syncthreads();
  }
#pragma unroll
  for (int m = 0; m < 4; m++) {
#pragma unroll
    for (int rg = 0; rg < 4; rg++) {
      int row = bm + wr * 64 + m * 16 + (lane >> 4) * 4 + rg;
      int s = row >> 9, nn = row & 511;
      size_t obase = (size_t)s * NB * CP;
#pragma unroll
      for (int n = 0; n < 4; n++) {
        int col = bn + wc * 64 + n * 16 + (lane & 15);
        if (col < NCOLS) {
          int b2 = col / C_CH, c = col - b2 * C_CH;
          Yb[obase + (size_t)(b2 * 512 + nn) * CP + c] = __float2bfloat16(acc[m][n][rg]);
        }
      }
    }
  }
}

// =================== MFMA GEMM 2: projection (M=OPAD, N=32, grid 1024) =========
// Block: 4 waves, wave wo owns rows [wo*OPAD/4,...) x all 32 cols.
// EPI 0 (gates): o<hd -> zh=sigmoid*HT -> XTo/XCo; o>=hd -> RG bf16.
// EPI 1 (upd):   hn = rg*HT+(1-rg)*tanh -> HT + XTo/XCo; + misc x[tnext] -> 4 bufs.
// EPI 2:         EPI1 + fused GO/out; GO + tt[tnext] -> 4 bufs.
template<int CP, int OPAD, int EPI, int CCH>
__global__ __launch_bounds__(256) void gemm_proj(
    const bf16* __restrict__ WT, const bf16* __restrict__ XCin,
    const bf16* __restrict__ Yb, const float* __restrict__ bias,
    bf16* __restrict__ RG, float* __restrict__ HT, int hd,
    const float* __restrict__ pW, const float* __restrict__ pb,
    float* __restrict__ outp, bf16* __restrict__ XTo, bf16* __restrict__ XCo,
    bf16* __restrict__ XTa, bf16* __restrict__ XCa, int t,
    const float* __restrict__ msrc, int tnext) {
  constexpr int MPW = OPAD / 4;          // rows per wave
  constexpr int MF  = MPW / 16;          // m-frags per wave
  __shared__ bf16 As[OPAD * 32];
  __shared__ bf16 Bs[32 * 32];
  __shared__ float red2[16 * 32];
  __shared__ float pws[128];
  const int tid = threadIdx.x, lane = tid & 63, wo = tid >> 6;
  int swb = (blockIdx.x & 7) * (gridDim.x >> 3) + (blockIdx.x >> 3);
  const int r0 = swb * 32;
  const int r_in = lane >> 2, dslot = lane & 3;

  if (EPI == 2 && tid < 128) pws[tid] = pW[tid];

  f4v acc[MF][2] = {};
#pragma unroll
  for (int seg = 0; seg < 5; seg++) {
    const bf16* Bbase = (seg == 0) ? XCin : (Yb + (size_t)(seg - 1) * NB * CP);
    const bf16* Abase = WT + (size_t)seg * OPAD * CP;
    for (int k0 = 0; k0 < CP; k0 += 32) {
      for (int ci = wo; ci < OPAD / 16; ci += 4) {
        int row = ci * 16 + r_in;
        int ss = dslot ^ ((row >> 1) & 3);
        glds16(Abase + (size_t)row * CP + k0 + ss * 8, As + ci * 512);
      }
      if (wo < 2) {
        int row = wo * 16 + r_in;
        int ss = dslot ^ ((row >> 1) & 3);
        glds16(Bbase + (size_t)(r0 + row) * CP + k0 + ss * 8, Bs + wo * 512);
      }
      asm volatile("s_waitcnt vmcnt(0)" ::: "memory");
      __syncthreads();
      s8v a[MF], bb[2];
#pragma unroll
      for (int m = 0; m < MF; m++) {
        int row = wo * MPW + m * 16 + (lane & 15);
        int slot = (lane >> 4) ^ ((row >> 1) & 3);
        a[m] = *(const s8v*)(As + row * 32 + slot * 8);
      }
#pragma unroll
      for (int n = 0; n < 2; n++) {
        int col = n * 16 + (lane & 15);
        int slot = (lane >> 4) ^ ((col >> 1) & 3);
        bb[n] = *(const s8v*)(Bs + col * 32 + slot * 8);
      }
#pragma unroll
      for (int m = 0; m < MF; m++)
#pragma unroll
        for (int n = 0; n < 2; n++)
          acc[m][n] = __builtin_amdgcn_mfma_f32_16x16x32_bf16(a[m], bb[n], acc[m][n], 0, 0, 0);
      __syncthreads();
    }
  }

#pragma unroll
  for (int m = 0; m < MF; m++) {
#pragma unroll
    for (int n = 0; n < 2; n++) {
      int r = r0 + n * 16 + (lane & 15);
      int b2 = r >> 9, nn = r & 511;
      int ch0 = wo * MPW + m * 16 + (lane >> 4) * 4;
      if (EPI == 0) {
        if (ch0 < hd) {
          bf16 z4[4];
#pragma unroll
          for (int rg = 0; rg < 4; rg++) {
            int o = ch0 + rg;
            float sg = 1.f / (1.f + expf(-(acc[m][n][rg] + bias[o])));
            float hold = HT[(size_t)o * NB + r];
            z4[rg] = __float2bfloat16(sg * hold);
            XTo[((size_t)b2 * CCH + o) * 512 + nn] = z4[rg];
          }
          *(s4v*)(XCo + (size_t)r * CP + ch0) = *(const s4v*)z4;
        } else {
#pragma unroll
          for (int rg = 0; rg < 4; rg++) {
            int o = ch0 + rg;
            float sg = 1.f / (1.f + expf(-(acc[m][n][rg] + bias[o])));
            RG[(size_t)(o - hd) * NB + r] = __float2bfloat16(sg);
          }
        }
      } else {
        if (ch0 < hd) {
          bf16 h4[4];
#pragma unroll
          for (int rg = 0; rg < 4; rg++) {
            int o = ch0 + rg;
            float hc = tanhf(acc[m][n][rg] + bias[o]);
            float rgt = __bfloat162float(RG[(size_t)o * NB + r]);
            float* hp = HT + (size_t)o * NB + r;
            float hn = rgt * (*hp) + (1.f - rgt) * hc;
            *hp = hn;
            h4[rg] = __float2bfloat16(hn);
            XTo[((size_t)b2 * CCH + o) * 512 + nn] = h4[rg];
            acc[m][n][rg] = hn;
          }
          *(s4v*)(XCo + (size_t)r * CP + ch0) = *(const s4v*)h4;
        }
      }
    }
  }

  // ---- EPI 1: fold next-step x misc channel into all 4 input buffers ----
  if (EPI == 1 && msrc != nullptr && tnext < L_ && tid < 32) {
    int r = r0 + tid;
    int b2 = r >> 9, nn = r & 511;
    bf16 v = __float2bfloat16(msrc[b2 * 6144 + nn * 12 + tnext]);
    XTo[((size_t)b2 * CCH + hd) * 512 + nn] = v;
    XCo[(size_t)r * CP + hd] = v;
    XTa[((size_t)b2 * CCH + hd) * 512 + nn] = v;
    XCa[(size_t)r * CP + hd] = v;
  }

  if (EPI == 2) {
    __syncthreads();
#pragma unroll
    for (int n = 0; n < 2; n++) {
      int r_local = n * 16 + (lane & 15);
      float ps = 0.f;
#pragma unroll
      for (int m = 0; m < MF; m++)
#pragma unroll
        for (int rg = 0; rg < 4; rg++) {
          int o = wo * MPW + m * 16 + (lane >> 4) * 4 + rg;
          ps += acc[m][n][rg] * pws[o];
        }
      red2[(wo * 4 + (lane >> 4)) * 32 + r_local] = ps;
    }
    __syncthreads();
    if (tid < 32) {
      float v = pb[0];
#pragma unroll
      for (int s2 = 0; s2 < 16; s2++) v += red2[s2 * 32 + tid];
      int r = r0 + tid;
      int b2 = r >> 9, nn = r & 511;
      outp[b2 * 6144 + nn * 12 + t] = v;
      bf16 gb = __float2bfloat16(v);
      XTo[((size_t)b2 * CCH + hd) * 512 + nn] = gb;
      XCo[(size_t)r * CP + hd] = gb;
      XTa[((size_t)b2 * CCH + hd) * 512 + nn] = gb;
      XCa[(size_t)r * CP + hd] = gb;
      // fold next-step tt channels into all 4 buffers
      if (msrc != nullptr && tnext < H_) {
#pragma unroll
        for (int ch = 0; ch < 5; ch++) {
          bf16 tv = __float2bfloat16(msrc[b2 * 60 + ch * 12 + tnext]);
          int c = hd + 1 + ch;
          XTo[((size_t)b2 * CCH + c) * 512 + nn] = tv;
          XCo[(size_t)r * CP + c] = tv;
          XTa[((size_t)b2 * CCH + c) * 512 + nn] = tv;
          XCa[(size_t)r * CP + c] = tv;
        }
      }
    }
  }
}

// =================== MFMA Chebyshev: O = 2*A@B - I ===========
__global__ __launch_bounds__(256) void gemm_cheb(
    const bf16* __restrict__ A, const bf16* __restrict__ BT, bf16* __restrict__ O) {
  __shared__ bf16 As[128 * 32];
  __shared__ bf16 Bs[128 * 32];
  const int tid = threadIdx.x, lane = tid & 63, wid = tid >> 6;
  const int wr = wid >> 1, wc = wid & 1;
  const int bm = blockIdx.y * 128, bn = blockIdx.x * 128;
  const int r_in = lane >> 2, dslot = lane & 3;
  f4v acc[4][4] = {};
  for (int k0 = 0; k0 < 512; k0 += 32) {
#pragma unroll
    for (int h = 0; h < 2; h++) {
      int ci = wid + h * 4;
      int row = ci * 16 + r_in;
      int ss = dslot ^ ((row >> 1) & 3);
      glds16(A + (size_t)(bm + row) * 512 + k0 + ss * 8, As + ci * 512);
      glds16(BT + (size_t)(bn + row) * 512 + k0 + ss * 8, Bs + ci * 512);
    }
    asm volatile("s_waitcnt vmcnt(0)" ::: "memory");
    __syncthreads();
    s8v a[4], bb[4];
#pragma unroll
    for (int m = 0; m < 4; m++) {
      int row = wr * 64 + m * 16 + (lane & 15);
      int slot = (lane >> 4) ^ ((row >> 1) & 3);
      a[m] = *(const s8v*)(As + row * 32 + slot * 8);
    }
#pragma unroll
    for (int n = 0; n < 4; n++) {
      int col = wc * 64 + n * 16 + (lane & 15);
      int slot = (lane >> 4) ^ ((col >> 1) & 3);
      bb[n] = *(const s8v*)(Bs + col * 32 + slot * 8);
    }
#pragma unroll
    for (int m = 0; m < 4; m++)
#pragma unroll
      for (int n = 0; n < 4; n++)
        acc[m][n] = __builtin_amdgcn_mfma_f32_16x16x32_bf16(a[m], bb[n], acc[m][n], 0, 0, 0);
    __syncthreads();
  }
#pragma unroll
  for (int m = 0; m < 4; m++) {
#pragma unroll
    for (int rg = 0; rg < 4; rg++) {
      int row = bm + wr * 64 + m * 16 + (lane >> 4) * 4 + rg;
#pragma unroll
      for (int n = 0; n < 4; n++) {
        int col = bn + wc * 64 + n * 16 + (lane & 15);
        float v = 2.f * acc[m][n][rg] - (row == col ? 1.f : 0.f);
        O[(size_t)row * 512 + col] = __float2bfloat16(v);
      }
    }
  }
}

// ---------------- small kernels ----------------
__global__ void fill_zero4(float4* p, int n) {
  for (int i = blockIdx.x * 256 + threadIdx.x; i < n; i += gridDim.x * 256)
    p[i] = make_float4(0.f, 0.f, 0.f, 0.f);
}

__global__ void compute_e(const float* __restrict__ We1, const float* __restrict__ We2,
                          const float* __restrict__ Mem, float* __restrict__ e1,
                          float* __restrict__ e2) {
  int idx = blockIdx.x * 256 + threadIdx.x;
  if (idx >= N_ * MEMD) return;
  int n = idx >> 6, d = idx & 63;
  float s1 = 0.f, s2 = 0.f;
  for (int k = 0; k < MEMN; k++) {
    float m = Mem[k * MEMD + d];
    s1 += We1[n * MEMN + k] * m;
    s2 += We2[n * MEMN + k] * m;
  }
  e1[idx] = s1; e2[idx] = s2;
}

__global__ void compute_wqm(const float* __restrict__ Wq, const float* __restrict__ Mem,
                            float* __restrict__ WqM) {
  int idx = blockIdx.x * 256 + threadIdx.x;
  if (idx >= RNN * MEMN) return;
  int c = idx / MEMN, j = idx - c * MEMN;
  float s = 0.f;
  for (int d = 0; d < MEMD; d++) s += Wq[c * MEMD + d] * Mem[j * MEMD + d];
  WqM[idx] = s;
}

__global__ void scores_relu(const float* __restrict__ e1, const float* __restrict__ e2,
                            float* __restrict__ S) {
  int idx = blockIdx.x * 256 + threadIdx.x;
  if (idx >= N_ * N_) return;
  int n = idx >> 9, m = idx & 511;
  float s = 0.f;
  for (int k = 0; k < MEMD; k++) s += e1[n * MEMD + k] * e2[m * MEMD + k];
  S[idx] = s > 0.f ? s : 0.f;
}

__global__ __launch_bounds__(256)
void row_softmax(const float* __restrict__ S, float* __restrict__ G) {
  int r = blockIdx.x;
  __shared__ float red[256];
  float m = -1e30f;
  for (int j = threadIdx.x; j < N_; j += 256) m = fmaxf(m, S[r * N_ + j]);
  red[threadIdx.x] = m; __syncthreads();
  for (int s = 128; s > 0; s >>= 1) {
    if (threadIdx.x < s) red[threadIdx.x] = fmaxf(red[threadIdx.x], red[threadIdx.x + s]);
    __syncthreads();
  }
  m = red[0]; __syncthreads();
  float sum = 0.f;
  for (int j = threadIdx.x; j < N_; j += 256) sum += expf(S[r * N_ + j] - m);
  red[threadIdx.x] = sum; __syncthreads();
  for (int s = 128; s > 0; s >>= 1) {
    if (threadIdx.x < s) red[threadIdx.x] += red[threadIdx.x + s];
    __syncthreads();
  }
  float inv = 1.f / red[0];
  for (int j = threadIdx.x; j < N_; j += 256)
    G[r * N_ + j] = expf(S[r * N_ + j] - m) * inv;
}

__global__ void trans_f32(const float* __restrict__ in, float* __restrict__ outT) {
  __shared__ float t[32][33];
  int bx = blockIdx.x * 32, by = blockIdx.y * 32;
  int x = threadIdx.x, y = threadIdx.y;           // block (32,8)
  for (int i = 0; i < 32; i += 8) t[y + i][x] = in[(by + y + i) * 512 + bx + x];
  __syncthreads();
  for (int i = 0; i < 32; i += 8) outT[(bx + y + i) * 512 + by + x] = t[x][y + i];
}

__global__ void trans_to_bf16(const float* __restrict__ in, bf16* __restrict__ outN,
                              bf16* __restrict__ outT) {
  __shared__ float t[32][33];
  int bx = blockIdx.x * 32, by = blockIdx.y * 32;
  int x = threadIdx.x, y = threadIdx.y;           // block (32,8)
  for (int i = 0; i < 32; i += 8) {
    float v = in[(by + y + i) * 512 + bx + x];
    t[y + i][x] = v;
    outN[(by + y + i) * 512 + bx + x] = __float2bfloat16(v);
  }
  __syncthreads();
  for (int i = 0; i < 32; i += 8)
    outT[(bx + y + i) * 512 + by + x] = __float2bfloat16(t[x][y + i]);
}

// WT[seg][Opad][CP]; permuted channels: c<HD -> ref row MC+c; HD<=c<HD+MC -> ref c-HD.
__global__ void prep_wt(const float* __restrict__ W, bf16* __restrict__ WT,
                        int C, int O, int Opad, int CP, int HD, int MC) {
  int idx = blockIdx.x * 256 + threadIdx.x;
  int tot = 5 * Opad * CP;
  if (idx >= tot) return;
  int seg = idx / (Opad * CP);
  int rem = idx - seg * (Opad * CP);
  int o = rem / CP, c = rem - (rem / CP) * CP;
  float v = 0.f;
  int srcc = -1;
  if (c < HD) srcc = MC + c;
  else if (c < HD + MC) srcc = c - HD;
  if (srcc >= 0 && o < O) {
    const int blkmap[5] = {0, 1, 2, 4, 5};
    int blk = blkmap[seg];
    v = W[(blk * C + srcc) * O + o];
    if (seg == 0) v += W[(3 * C + srcc) * O + o];
  }
  WT[idx] = __float2bfloat16(v);
}

// ---- t=0 misc fills ----
__global__ void fill_misc_enc(bf16* __restrict__ XTh, bf16* __restrict__ XTz,
                              bf16* __restrict__ XCh, bf16* __restrict__ XCz,
                              const float* __restrict__ x, int t) {
  int r = blockIdx.x * 256 + threadIdx.x;
  if (r >= NB) return;
  int b = r >> 9, n = r & 511;
  bf16 v = __float2bfloat16(x[b * 6144 + n * 12 + t]);
  XTh[((size_t)b * 65 + 64) * 512 + n] = v;
  XTz[((size_t)b * 65 + 64) * 512 + n] = v;
  XCh[(size_t)r * 96 + 64] = v;
  XCz[(size_t)r * 96 + 64] = v;
}

__global__ void fill_misc_dec(bf16* __restrict__ XTh, bf16* __restrict__ XTz,
                              bf16* __restrict__ XCh, bf16* __restrict__ XCz,
                              const float* __restrict__ tt, int t, int writego) {
  int idx = blockIdx.x * 256 + threadIdx.x;
  if (idx >= NB * 6) return;
  int ch = idx >> 15, r = idx & (NB - 1);
  int b = r >> 9, n = r & 511;
  bf16 v;
  int c;
  if (ch < 5) { v = __float2bfloat16(tt[b * 60 + ch * 12 + t]); c = 129 + ch; }
  else { if (!writego) return; v = __float2bfloat16(0.f); c = 128; }
  XTh[((size_t)b * 134 + c) * 512 + n] = v;
  XTz[((size_t)b * 134 + c) * 512 + n] = v;
  XCh[(size_t)r * 160 + c] = v;
  XCz[(size_t)r * 160 + c] = v;
}

// ---- attention: seeds dec gates input ----
__global__ __launch_bounds__(128) void attention2(
    const float* __restrict__ HbT, const float* __restrict__ WqM,
    const float* __restrict__ Mem, float* __restrict__ HdT,
    bf16* __restrict__ XTh, bf16* __restrict__ XCh) {
  __shared__ float h[64][128];
  __shared__ float wqm[64][20];
  __shared__ float mem[20][64];
  const int tid = threadIdx.x, r0 = blockIdx.x * 128;
  const int r = r0 + tid, b = r >> 9, n = r & 511;
  for (int e = tid; e < 64 * 128; e += 128) {
    int c = e >> 7, j = e & 127;
    h[c][j] = HbT[(size_t)c * NB + r0 + j];
  }
  for (int e = tid; e < 1280; e += 128) {
    wqm[e / 20][e % 20] = WqM[e];
    mem[e >> 6][e & 63] = Mem[e];
  }
  __syncthreads();
  float s[20];
#pragma unroll
  for (int j = 0; j < 20; j++) s[j] = 0.f;
  for (int c = 0; c < 64; c++) {
    float hv = h[c][tid];
#pragma unroll
    for (int j = 0; j < 20; j++) s[j] += hv * wqm[c][j];
  }
  float mx = s[0];
#pragma unroll
  for (int j = 1; j < 20; j++) mx = fmaxf(mx, s[j]);
  float sum = 0.f;
#pragma unroll
  for (int j = 0; j < 20; j++) { s[j] = expf(s[j] - mx); sum += s[j]; }
  float inv = 1.f / sum;
#pragma unroll
  for (int j = 0; j < 20; j++) s[j] *= inv;
  for (int d = 0; d < 64; d++) {
    float ha = 0.f;
#pragma unroll
    for (int j = 0; j < 20; j++) ha += s[j] * mem[j][d];
    float hv = h[d][tid];
    HdT[(size_t)d * NB + r] = hv;
    HdT[(size_t)(64 + d) * NB + r] = ha;
    bf16 hb = __float2bfloat16(hv), ab = __float2bfloat16(ha);
    XTh[((size_t)b * 134 + d) * 512 + n] = hb;
    XTh[((size_t)b * 134 + 64 + d) * 512 + n] = ab;
    XCh[(size_t)r * 160 + d] = hb;
    XCh[(size_t)r * 160 + 64 + d] = ab;
  }
}

// ---------------- host ----------------
extern "C" void kernel_launch(void* const* d_in, const int* in_sizes, int n_in,
                              void* d_out, int out_size, void* d_ws, size_t ws_size,
                              hipStream_t stream) {
  const float* x   = (const float*)d_in[0];
  const float* tt  = (const float*)d_in[3];
  const float* Mem = (const float*)d_in[5];
  const float* Wq  = (const float*)d_in[6];
  const float* We1 = (const float*)d_in[7];
  const float* We2 = (const float*)d_in[8];
  const float* egW = (const float*)d_in[9];
  const float* egb = (const float*)d_in[10];
  const float* euW = (const float*)d_in[11];
  const float* eub = (const float*)d_in[12];
  const float* dgW = (const float*)d_in[13];
  const float* dgb = (const float*)d_in[14];
  const float* duW = (const float*)d_in[15];
  const float* dub = (const float*)d_in[16];
  const float* pW  = (const float*)d_in[17];
  const float* pb  = (const float*)d_in[18];
  float* out = (float*)d_out;

  char* ws = (char*)d_ws;
  size_t off = 0;
  auto alloc = [&](size_t bytes) { char* p = ws + off; off += (bytes + 255) & ~(size_t)255; return p; };
  // ---- zeroed-at-launch-start region ----
  bf16* XTh   = (bf16*)alloc((size_t)8576 * 512 * 2);
  bf16* XCh   = (bf16*)alloc((size_t)NB * 160 * 2);
  float* HbT  = (float*)alloc((size_t)RNN * NB * 4);
  size_t zero_bytes = off;
  // ---- rest ----
  bf16* XTz   = (bf16*)alloc((size_t)8576 * 512 * 2);
  bf16* XCz   = (bf16*)alloc((size_t)NB * 160 * 2);
  bf16* Ybuf  = (bf16*)alloc((size_t)4 * NB * 160 * 2);
  bf16* RG    = (bf16*)alloc((size_t)DD * NB * 2);
  bf16* WTeg  = (bf16*)alloc((size_t)5 * 128 * 96 * 2);
  bf16* WTeu  = (bf16*)alloc((size_t)5 * 64 * 96 * 2);
  bf16* WTdg  = (bf16*)alloc((size_t)5 * 256 * 160 * 2);
  bf16* WTdu  = (bf16*)alloc((size_t)5 * 128 * 160 * 2);
  bf16* Sb    = (bf16*)alloc((size_t)4 * 512 * 512 * 2);
  bf16* g1T   = (bf16*)alloc((size_t)512 * 512 * 2);
  bf16* g2T   = (bf16*)alloc((size_t)512 * 512 * 2);
  float* HdT  = (float*)alloc((size_t)DD * NB * 4);
  float* WqM  = (float*)alloc((size_t)RNN * MEMN * 4);
  float* e1   = (float*)alloc((size_t)N_ * MEMD * 4);
  float* e2   = (float*)alloc((size_t)N_ * MEMD * 4);
  float* S    = (float*)alloc((size_t)N_ * N_ * 4);
  float* ST   = (float*)alloc((size_t)N_ * N_ * 4);
  float* g1f  = (float*)alloc((size_t)N_ * N_ * 4);
  float* g2f  = (float*)alloc((size_t)N_ * N_ * 4);

  auto blk = [](long n) { return dim3((unsigned)((n + 255) / 256)); };

  // ---- phase 0 ----
  fill_zero4<<<2048, 256, 0, stream>>>((float4*)ws, (int)(zero_bytes / 16));
  compute_e<<<blk(N_ * MEMD), 256, 0, stream>>>(We1, We2, Mem, e1, e2);
  compute_wqm<<<blk(RNN * MEMN), 256, 0, stream>>>(Wq, Mem, WqM);
  scores_relu<<<blk(N_ * N_), 256, 0, stream>>>(e1, e2, S);
  trans_f32<<<dim3(16, 16), dim3(32, 8), 0, stream>>>(S, ST);
  row_softmax<<<N_, 256, 0, stream>>>(S, g1f);
  row_softmax<<<N_, 256, 0, stream>>>(ST, g2f);
  trans_to_bf16<<<dim3(16, 16), dim3(32, 8), 0, stream>>>(g1f, Sb + 0 * 262144, g1T);
  trans_to_bf16<<<dim3(16, 16), dim3(32, 8), 0, stream>>>(g2f, Sb + 2 * 262144, g2T);
  gemm_cheb<<<dim3(4, 4), 256, 0, stream>>>(Sb + 0 * 262144, g1T, Sb + 1 * 262144);
  gemm_cheb<<<dim3(4, 4), 256, 0, stream>>>(Sb + 2 * 262144, g2T, Sb + 3 * 262144);
  prep_wt<<<blk(5 * 128 * 96), 256, 0, stream>>>(egW, WTeg, 65, 128, 128, 96, 64, 1);
  prep_wt<<<blk(5 * 64 * 96), 256, 0, stream>>>(euW, WTeu, 65, 64, 64, 96, 64, 1);
  prep_wt<<<blk(5 * 256 * 160), 256, 0, stream>>>(dgW, WTdg, 134, 256, 256, 160, 128, 6);
  prep_wt<<<blk(5 * 128 * 160), 256, 0, stream>>>(duW, WTdu, 134, 128, 128, 160, 128, 6);

  // ---- encoder ----
  fill_misc_enc<<<blk(NB), 256, 0, stream>>>(XTh, XTz, XCh, XCz, x, 0);
  for (int t = 0; t < L_; t++) {
    gemm_mix<65, 96><<<dim3(33, 16), 256, 0, stream>>>(Sb, XTh, Ybuf);
    gemm_proj<96, 128, 0, 65><<<1024, 256, 0, stream>>>(
        WTeg, XCh, Ybuf, egb, RG, HbT, RNN, nullptr, nullptr, nullptr,
        XTz, XCz, nullptr, nullptr, 0, nullptr, 99);
    gemm_mix<65, 96><<<dim3(33, 16), 256, 0, stream>>>(Sb, XTz, Ybuf);
    gemm_proj<96, 64, 1, 65><<<1024, 256, 0, stream>>>(
        WTeu, XCz, Ybuf, eub, RG, HbT, RNN, nullptr, nullptr, nullptr,
        XTh, XCh, XTz, XCz, 0, x, t + 1);
  }

  // ---- attention -> HdT + seed dec gates input ----
  attention2<<<dim3(256), 128, 0, stream>>>(HbT, WqM, Mem, HdT, XTh, XCh);

  // ---- decoder ----
  fill_misc_dec<<<blk((long)NB * 6), 256, 0, stream>>>(XTh, XTz, XCh, XCz, tt, 0, 1);
  for (int t = 0; t < H_; t++) {
    gemm_mix<134, 160><<<dim3(67, 16), 256, 0, stream>>>(Sb, XTh, Ybuf);
    gemm_proj<160, 256, 0, 134><<<1024, 256, 0, stream>>>(
        WTdg, XCh, Ybuf, dgb, RG, HdT, DD, nullptr, nullptr, nullptr,
        XTz, XCz, nullptr, nullptr, 0, nullptr, 99);
    gemm_mix<134, 160><<<dim3(67, 16), 256, 0, stream>>>(Sb, XTz, Ybuf);
    gemm_proj<160, 128, 2, 134><<<1024, 256, 0, stream>>>(
        WTdu, XCz, Ybuf, dub, RG, HdT, DD, pW, pb, out,
        XTh, XCh, XTz, XCz, t, tt, t + 1);
  }
}

// Round 26
// 2546.764 us; speedup vs baseline: 1.0028x; 1.0010x over previous
//
#include <hip/hip_runtime.h>
#include <hip/hip_bf16.h>
#include <math.h>

typedef __hip_bfloat16 bf16;
typedef __attribute__((ext_vector_type(8))) short s8v;
typedef __attribute__((ext_vector_type(4))) short s4v;
typedef __attribute__((ext_vector_type(4))) float f4v;

#define B_   64
#define N_   512
#define L_   12
#define H_   12
#define RNN  64
#define MEMN 20
#define MEMD 64
#define DD   128
#define NB   32768          // N_*B_ ; r = b*512 + n (b-major)

// Channel layout (permuted): c in [0,HD) = h-channels; c in [HD,HD+MC) = misc
// (enc: HD=64, MC=1 (x); dec: HD=128, MC=6 (go,tt0..4)); c >= HD+MC pad (W=0).

// ---------- global->LDS 16B DMA ----------
__device__ inline void glds16(const bf16* g, bf16* l) {
  __builtin_amdgcn_global_load_lds((const __attribute__((address_space(1))) void*)g,
                                   (__attribute__((address_space(3))) void*)l, 16, 0, 0);
}

// ---------- XCD-aware bijective swizzle (2-D grid) ----------
__device__ inline int2 xcd_swz() {
  int lid = blockIdx.x + blockIdx.y * gridDim.x;
  int chunk = (gridDim.x * gridDim.y) >> 3;
  int swz = (lid & 7) * chunk + (lid >> 3);
  int bx = swz / gridDim.y;
  int by = swz - bx * gridDim.y;
  return make_int2(bx, by);
}

// =================== MFMA GEMM 1: graph mix (R4 structure + XCD swizzle) =======
template<int C_CH, int CP>
__global__ __launch_bounds__(256) void gemm_mix(
    const bf16* __restrict__ Sb, const bf16* __restrict__ XT, bf16* __restrict__ Yb) {
  const int NCOLS = 64 * C_CH;
  __shared__ bf16 As[128 * 32];
  __shared__ bf16 Bs[128 * 32];
  const int tid = threadIdx.x, lane = tid & 63, wid = tid >> 6;
  const int wr = wid >> 1, wc = wid & 1;
  int2 sz = xcd_swz();
  const int bn = sz.x * 128, bm = sz.y * 128;
  const int r_in = lane >> 2, dslot = lane & 3;
  f4v acc[4][4] = {};
  for (int k0 = 0; k0 < 512; k0 += 32) {
#pragma unroll
    for (int h = 0; h < 2; h++) {
      int ci = wid + h * 4;
      int row = ci * 16 + r_in;
      int ss = dslot ^ ((row >> 1) & 3);
      glds16(Sb + (size_t)(bm + row) * 512 + k0 + ss * 8, As + ci * 512);
      glds16(XT + (size_t)(bn + row) * 512 + k0 + ss * 8, Bs + ci * 512);
    }
    asm volatile("s_waitcnt vmcnt(0)" ::: "memory");
    __syncthreads();
    s8v a[4], bb[4];
#pragma unroll
    for (int m = 0; m < 4; m++) {
      int row = wr * 64 + m * 16 + (lane & 15);
      int slot = (lane >> 4) ^ ((row >> 1) & 3);
      a[m] = *(const s8v*)(As + row * 32 + slot * 8);
    }
#pragma unroll
    for (int n = 0; n < 4; n++) {
      int col = wc * 64 + n * 16 + (lane & 15);
      int slot = (lane >> 4) ^ ((col >> 1) & 3);
      bb[n] = *(const s8v*)(Bs + col * 32 + slot * 8);
    }
#pragma unroll
    for (int m = 0; m < 4; m++)
#pragma unroll
      for (int n = 0; n < 4; n++)
        acc[m][n] = __builtin_amdgcn_mfma_f32_16x16x32_bf16(a[m], bb[n], acc[m][n], 0, 0, 0);
    __syncthreads();
  }
#pragma unroll
  for (int m = 0; m < 4; m++) {
#pragma unroll
    for (int rg = 0; rg < 4; rg++) {
      int row = bm + wr * 64 + m * 16 + (lane >> 4) * 4 + rg;
      int s = row >> 9, nn = row & 511;
      size_t obase = (size_t)s * NB * CP;
#pragma unroll
      for (int n = 0; n < 4; n++) {
        int col = bn + wc * 64 + n * 16 + (lane & 15);
        if (col < NCOLS) {
          int b2 = col / C_CH, c = col - b2 * C_CH;
          Yb[obase + (size_t)(b2 * 512 + nn) * CP + c] = __float2bfloat16(acc[m][n][rg]);
        }
      }
    }
  }
}

// =================== MFMA GEMM 2: projection (M=OPAD, N=32, grid 1024) =========
// Block: 4 waves, wave wo owns rows [wo*OPAD/4,...) x all 32 cols.
// EPI 0 (gates): o<hd -> zh=sigmoid*HT -> XTo/XCo; o>=hd -> RG bf16.
// EPI 1 (upd):   hn = rg*HT+(1-rg)*tanh -> HT + XTo/XCo; + misc x[tnext] -> 4 bufs.
// EPI 2:         EPI1 + fused GO/out; GO + tt[tnext] -> 4 bufs.
template<int CP, int OPAD, int EPI, int CCH>
__global__ __launch_bounds__(256) void gemm_proj(
    const bf16* __restrict__ WT, const bf16* __restrict__ XCin,
    const bf16* __restrict__ Yb, const float* __restrict__ bias,
    bf16* __restrict__ RG, float* __restrict__ HT, int hd,
    const float* __restrict__ pW, const float* __restrict__ pb,
    float* __restrict__ outp, bf16* __restrict__ XTo, bf16* __restrict__ XCo,
    bf16* __restrict__ XTa, bf16* __restrict__ XCa, int t,
    const float* __restrict__ msrc, int tnext) {
  constexpr int MPW = OPAD / 4;          // rows per wave
  constexpr int MF  = MPW / 16;          // m-frags per wave
  __shared__ bf16 As[OPAD * 32];
  __shared__ bf16 Bs[32 * 32];
  __shared__ float red2[16 * 32];
  __shared__ float pws[128];
  const int tid = threadIdx.x, lane = tid & 63, wo = tid >> 6;
  int swb = (blockIdx.x & 7) * (gridDim.x >> 3) + (blockIdx.x >> 3);
  const int r0 = swb * 32;
  const int r_in = lane >> 2, dslot = lane & 3;

  if (EPI == 2 && tid < 128) pws[tid] = pW[tid];

  f4v acc[MF][2] = {};
#pragma unroll
  for (int seg = 0; seg < 5; seg++) {
    const bf16* Bbase = (seg == 0) ? XCin : (Yb + (size_t)(seg - 1) * NB * CP);
    const bf16* Abase = WT + (size_t)seg * OPAD * CP;
    for (int k0 = 0; k0 < CP; k0 += 32) {
      for (int ci = wo; ci < OPAD / 16; ci += 4) {
        int row = ci * 16 + r_in;
        int ss = dslot ^ ((row >> 1) & 3);
        glds16(Abase + (size_t)row * CP + k0 + ss * 8, As + ci * 512);
      }
      if (wo < 2) {
        int row = wo * 16 + r_in;
        int ss = dslot ^ ((row >> 1) & 3);
        glds16(Bbase + (size_t)(r0 + row) * CP + k0 + ss * 8, Bs + wo * 512);
      }
      asm volatile("s_waitcnt vmcnt(0)" ::: "memory");
      __syncthreads();
      s8v a[MF], bb[2];
#pragma unroll
      for (int m = 0; m < MF; m++) {
        int row = wo * MPW + m * 16 + (lane & 15);
        int slot = (lane >> 4) ^ ((row >> 1) & 3);
        a[m] = *(const s8v*)(As + row * 32 + slot * 8);
      }
#pragma unroll
      for (int n = 0; n < 2; n++) {
        int col = n * 16 + (lane & 15);
        int slot = (lane >> 4) ^ ((col >> 1) & 3);
        bb[n] = *(const s8v*)(Bs + col * 32 + slot * 8);
      }
#pragma unroll
      for (int m = 0; m < MF; m++)
#pragma unroll
        for (int n = 0; n < 2; n++)
          acc[m][n] = __builtin_amdgcn_mfma_f32_16x16x32_bf16(a[m], bb[n], acc[m][n], 0, 0, 0);
      __syncthreads();
    }
  }

#pragma unroll
  for (int m = 0; m < MF; m++) {
#pragma unroll
    for (int n = 0; n < 2; n++) {
      int r = r0 + n * 16 + (lane & 15);
      int b2 = r >> 9, nn = r & 511;
      int ch0 = wo * MPW + m * 16 + (lane >> 4) * 4;
      if (EPI == 0) {
        if (ch0 < hd) {
          bf16 z4[4];
#pragma unroll
          for (int rg = 0; rg < 4; rg++) {
            int o = ch0 + rg;
            float sg = 1.f / (1.f + expf(-(acc[m][n][rg] + bias[o])));
            float hold = HT[(size_t)o * NB + r];
            z4[rg] = __float2bfloat16(sg * hold);
            XTo[((size_t)b2 * CCH + o) * 512 + nn] = z4[rg];
          }
          *(s4v*)(XCo + (size_t)r * CP + ch0) = *(const s4v*)z4;
        } else {
#pragma unroll
          for (int rg = 0; rg < 4; rg++) {
            int o = ch0 + rg;
            float sg = 1.f / (1.f + expf(-(acc[m][n][rg] + bias[o])));
            RG[(size_t)(o - hd) * NB + r] = __float2bfloat16(sg);
          }
        }
      } else {
        if (ch0 < hd) {
          bf16 h4[4];
#pragma unroll
          for (int rg = 0; rg < 4; rg++) {
            int o = ch0 + rg;
            float hc = tanhf(acc[m][n][rg] + bias[o]);
            float rgt = __bfloat162float(RG[(size_t)o * NB + r]);
            float* hp = HT + (size_t)o * NB + r;
            float hn = rgt * (*hp) + (1.f - rgt) * hc;
            *hp = hn;
            h4[rg] = __float2bfloat16(hn);
            XTo[((size_t)b2 * CCH + o) * 512 + nn] = h4[rg];
            acc[m][n][rg] = hn;
          }
          *(s4v*)(XCo + (size_t)r * CP + ch0) = *(const s4v*)h4;
        }
      }
    }
  }

  // ---- EPI 1: fold next-step x misc channel into all 4 input buffers ----
  if (EPI == 1 && msrc != nullptr && tnext < L_ && tid < 32) {
    int r = r0 + tid;
    int b2 = r >> 9, nn = r & 511;
    bf16 v = __float2bfloat16(msrc[b2 * 6144 + nn * 12 + tnext]);
    XTo[((size_t)b2 * CCH + hd) * 512 + nn] = v;
    XCo[(size_t)r * CP + hd] = v;
    XTa[((size_t)b2 * CCH + hd) * 512 + nn] = v;
    XCa[(size_t)r * CP + hd] = v;
  }

  if (EPI == 2) {
    __syncthreads();
#pragma unroll
    for (int n = 0; n < 2; n++) {
      int r_local = n * 16 + (lane & 15);
      float ps = 0.f;
#pragma unroll
      for (int m = 0; m < MF; m++)
#pragma unroll
        for (int rg = 0; rg < 4; rg++) {
          int o = wo * MPW + m * 16 + (lane >> 4) * 4 + rg;
          ps += acc[m][n][rg] * pws[o];
        }
      red2[(wo * 4 + (lane >> 4)) * 32 + r_local] = ps;
    }
    __syncthreads();
    if (tid < 32) {
      float v = pb[0];
#pragma unroll
      for (int s2 = 0; s2 < 16; s2++) v += red2[s2 * 32 + tid];
      int r = r0 + tid;
      int b2 = r >> 9, nn = r & 511;
      outp[b2 * 6144 + nn * 12 + t] = v;
      bf16 gb = __float2bfloat16(v);
      XTo[((size_t)b2 * CCH + hd) * 512 + nn] = gb;
      XCo[(size_t)r * CP + hd] = gb;
      XTa[((size_t)b2 * CCH + hd) * 512 + nn] = gb;
      XCa[(size_t)r * CP + hd] = gb;
      // fold next-step tt channels into all 4 buffers
      if (msrc != nullptr && tnext < H_) {
#pragma unroll
        for (int ch = 0; ch < 5; ch++) {
          bf16 tv = __float2bfloat16(msrc[b2 * 60 + ch * 12 + tnext]);
          int c = hd + 1 + ch;
          XTo[((size_t)b2 * CCH + c) * 512 + nn] = tv;
          XCo[(size_t)r * CP + c] = tv;
          XTa[((size_t)b2 * CCH + c) * 512 + nn] = tv;
          XCa[(size_t)r * CP + c] = tv;
        }
      }
    }
  }
}

// =================== MFMA Chebyshev: O = 2*A@B - I ===========
__global__ __launch_bounds__(256) void gemm_cheb(
    const bf16* __restrict__ A, const bf16* __restrict__ BT, bf16* __restrict__ O) {
  __shared__ bf16 As[128 * 32];
  __shared__ bf16 Bs[128 * 32];
  const int tid = threadIdx.x, lane = tid & 63, wid = tid >> 6;
  const int wr = wid >> 1, wc = wid & 1;
  const int bm = blockIdx.y * 128, bn = blockIdx.x * 128;
  const int r_in = lane >> 2, dslot = lane & 3;
  f4v acc[4][4] = {};
  for (int k0 = 0; k0 < 512; k0 += 32) {
#pragma unroll
    for (int h = 0; h < 2; h++) {
      int ci = wid + h * 4;
      int row = ci * 16 + r_in;
      int ss = dslot ^ ((row >> 1) & 3);
      glds16(A + (size_t)(bm + row) * 512 + k0 + ss * 8, As + ci * 512);
      glds16(BT + (size_t)(bn + row) * 512 + k0 + ss * 8, Bs + ci * 512);
    }
    asm volatile("s_waitcnt vmcnt(0)" ::: "memory");
    __syncthreads();
    s8v a[4], bb[4];
#pragma unroll
    for (int m = 0; m < 4; m++) {
      int row = wr * 64 + m * 16 + (lane & 15);
      int slot = (lane >> 4) ^ ((row >> 1) & 3);
      a[m] = *(const s8v*)(As + row * 32 + slot * 8);
    }
#pragma unroll
    for (int n = 0; n < 4; n++) {
      int col = wc * 64 + n * 16 + (lane & 15);
      int slot = (lane >> 4) ^ ((col >> 1) & 3);
      bb[n] = *(const s8v*)(Bs + col * 32 + slot * 8);
    }
#pragma unroll
    for (int m = 0; m < 4; m++)
#pragma unroll
      for (int n = 0; n < 4; n++)
        acc[m][n] = __builtin_amdgcn_mfma_f32_16x16x32_bf16(a[m], bb[n], acc[m][n], 0, 0, 0);
    __syncthreads();
  }
#pragma unroll
  for (int m = 0; m < 4; m++) {
#pragma unroll
    for (int rg = 0; rg < 4; rg++) {
      int row = bm + wr * 64 + m * 16 + (lane >> 4) * 4 + rg;
#pragma unroll
      for (int n = 0; n < 4; n++) {
        int col = bn + wc * 64 + n * 16 + (lane & 15);
        float v = 2.f * acc[m][n][rg] - (row == col ? 1.f : 0.f);
        O[(size_t)row * 512 + col] = __float2bfloat16(v);
      }
    }
  }
}

// ---------------- small kernels ----------------
__global__ void fill_zero4(float4* p, int n) {
  for (int i = blockIdx.x * 256 + threadIdx.x; i < n; i += gridDim.x * 256)
    p[i] = make_float4(0.f, 0.f, 0.f, 0.f);
}

__global__ void compute_e(const float* __restrict__ We1, const float* __restrict__ We2,
                          const float* __restrict__ Mem, float* __restrict__ e1,
                          float* __restrict__ e2) {
  int idx = blockIdx.x * 256 + threadIdx.x;
  if (idx >= N_ * MEMD) return;
  int n = idx >> 6, d = idx & 63;
  float s1 = 0.f, s2 = 0.f;
  for (int k = 0; k < MEMN; k++) {
    float m = Mem[k * MEMD + d];
    s1 += We1[n * MEMN + k] * m;
    s2 += We2[n * MEMN + k] * m;
  }
  e1[idx] = s1; e2[idx] = s2;
}

__global__ void compute_wqm(const float* __restrict__ Wq, const float* __restrict__ Mem,
                            float* __restrict__ WqM) {
  int idx = blockIdx.x * 256 + threadIdx.x;
  if (idx >= RNN * MEMN) return;
  int c = idx / MEMN, j = idx - c * MEMN;
  float s = 0.f;
  for (int d = 0; d < MEMD; d++) s += Wq[c * MEMD + d] * Mem[j * MEMD + d];
  WqM[idx] = s;
}

__global__ void scores_relu(const float* __restrict__ e1, const float* __restrict__ e2,
                            float* __restrict__ S) {
  int idx = blockIdx.x * 256 + threadIdx.x;
  if (idx >= N_ * N_) return;
  int n = idx >> 9, m = idx & 511;
  float s = 0.f;
  for (int k = 0; k < MEMD; k++) s += e1[n * MEMD + k] * e2[m * MEMD + k];
  S[idx] = s > 0.f ? s : 0.f;
}

__global__ __launch_bounds__(256)
void row_softmax(const float* __restrict__ S, float* __restrict__ G) {
  int r = blockIdx.x;
  __shared__ float red[256];
  float m = -1e30f;
  for (int j = threadIdx.x; j < N_; j += 256) m = fmaxf(m, S[r * N_ + j]);
  red[threadIdx.x] = m; __syncthreads();
  for (int s = 128; s > 0; s >>= 1) {
    if (threadIdx.x < s) red[threadIdx.x] = fmaxf(red[threadIdx.x], red[threadIdx.x + s]);
    __syncthreads();
  }
  m = red[0]; __syncthreads();
  float sum = 0.f;
  for (int j = threadIdx.x; j < N_; j += 256) sum += expf(S[r * N_ + j] - m);
  red[threadIdx.x] = sum; __syncthreads();
  for (int s = 128; s > 0; s >>= 1) {
    if (threadIdx.x < s) red[threadIdx.x] += red[threadIdx.x + s];
    __syncthreads();
  }
  float inv = 1.f / red[0];
  for (int j = threadIdx.x; j < N_; j += 256)
    G[r * N_ + j] = expf(S[r * N_ + j] - m) * inv;
}

__global__ void trans_f32(const float* __restrict__ in, float* __restrict__ outT) {
  __shared__ float t[32][33];
  int bx = blockIdx.x * 32, by = blockIdx.y * 32;
  int x = threadIdx.x, y = threadIdx.y;           // block (32,8)
  for (int i = 0; i < 32; i += 8) t[y + i][x] = in[(by + y + i) * 512 + bx + x];
  __syncthreads();
  for (int i = 0; i < 32; i += 8) outT[(bx + y + i) * 512 + by + x] = t[x][y + i];
}

__global__ void trans_to_bf16(const float* __restrict__ in, bf16* __restrict__ outN,
                              bf16* __restrict__ outT) {
  __shared__ float t[32][33];
  int bx = blockIdx.x * 32, by = blockIdx.y * 32;
  int x = threadIdx.x, y = threadIdx.y;           // block (32,8)
  for (int i = 0; i < 32; i += 8) {
    float v = in[(by + y + i) * 512 + bx + x];
    t[y + i][x] = v;
    outN[(by + y + i) * 512 + bx + x] = __float2bfloat16(v);
  }
  __syncthreads();
  for (int i = 0; i < 32; i += 8)
    outT[(bx + y + i) * 512 + by + x] = __float2bfloat16(t[x][y + i]);
}

// WT[seg][Opad][CP]; permuted channels: c<HD -> ref row MC+c; HD<=c<HD+MC -> ref c-HD.
__global__ void prep_wt(const float* __restrict__ W, bf16* __restrict__ WT,
                        int C, int O, int Opad, int CP, int HD, int MC) {
  int idx = blockIdx.x * 256 + threadIdx.x;
  int tot = 5 * Opad * CP;
  if (idx >= tot) return;
  int seg = idx / (Opad * CP);
  int rem = idx - seg * (Opad * CP);
  int o = rem / CP, c = rem - (rem / CP) * CP;
  float v = 0.f;
  int srcc = -1;
  if (c < HD) srcc = MC + c;
  else if (c < HD + MC) srcc = c - HD;
  if (srcc >= 0 && o < O) {
    const int blkmap[5] = {0, 1, 2, 4, 5};
    int blk = blkmap[seg];
    v = W[(blk * C + srcc) * O + o];
    if (seg == 0) v += W[(3 * C + srcc) * O + o];
  }
  WT[idx] = __float2bfloat16(v);
}

// ---- t=0 misc fills ----
__global__ void fill_misc_enc(bf16* __restrict__ XTh, bf16* __restrict__ XTz,
                              bf16* __restrict__ XCh, bf16* __restrict__ XCz,
                              const float* __restrict__ x, int t) {
  int r = blockIdx.x * 256 + threadIdx.x;
  if (r >= NB) return;
  int b = r >> 9, n = r & 511;
  bf16 v = __float2bfloat16(x[b * 6144 + n * 12 + t]);
  XTh[((size_t)b * 65 + 64) * 512 + n] = v;
  XTz[((size_t)b * 65 + 64) * 512 + n] = v;
  XCh[(size_t)r * 96 + 64] = v;
  XCz[(size_t)r * 96 + 64] = v;
}

__global__ void fill_misc_dec(bf16* __restrict__ XTh, bf16* __restrict__ XTz,
                              bf16* __restrict__ XCh, bf16* __restrict__ XCz,
                              const float* __restrict__ tt, int t, int writego) {
  int idx = blockIdx.x * 256 + threadIdx.x;
  if (idx >= NB * 6) return;
  int ch = idx >> 15, r = idx & (NB - 1);
  int b = r >> 9, n = r & 511;
  bf16 v;
  int c;
  if (ch < 5) { v = __float2bfloat16(tt[b * 60 + ch * 12 + t]); c = 129 + ch; }
  else { if (!writego) return; v = __float2bfloat16(0.f); c = 128; }
  XTh[((size_t)b * 134 + c) * 512 + n] = v;
  XTz[((size_t)b * 134 + c) * 512 + n] = v;
  XCh[(size_t)r * 160 + c] = v;
  XCz[(size_t)r * 160 + c] = v;
}

// ---- attention: seeds dec gates input ----
__global__ __launch_bounds__(128) void attention2(
    const float* __restrict__ HbT, const float* __restrict__ WqM,
    const float* __restrict__ Mem, float* __restrict__ HdT,
    bf16* __restrict__ XTh, bf16* __restrict__ XCh) {
  __shared__ float h[64][128];
  __shared__ float wqm[64][20];
  __shared__ float mem[20][64];
  const int tid = threadIdx.x, r0 = blockIdx.x * 128;
  const int r = r0 + tid, b = r >> 9, n = r & 511;
  for (int e = tid; e < 64 * 128; e += 128) {
    int c = e >> 7, j = e & 127;
    h[c][j] = HbT[(size_t)c * NB + r0 + j];
  }
  for (int e = tid; e < 1280; e += 128) {
    wqm[e / 20][e % 20] = WqM[e];
    mem[e >> 6][e & 63] = Mem[e];
  }
  __syncthreads();
  float s[20];
#pragma unroll
  for (int j = 0; j < 20; j++) s[j] = 0.f;
  for (int c = 0; c < 64; c++) {
    float hv = h[c][tid];
#pragma unroll
    for (int j = 0; j < 20; j++) s[j] += hv * wqm[c][j];
  }
  float mx = s[0];
#pragma unroll
  for (int j = 1; j < 20; j++) mx = fmaxf(mx, s[j]);
  float sum = 0.f;
#pragma unroll
  for (int j = 0; j < 20; j++) { s[j] = expf(s[j] - mx); sum += s[j]; }
  float inv = 1.f / sum;
#pragma unroll
  for (int j = 0; j < 20; j++) s[j] *= inv;
  for (int d = 0; d < 64; d++) {
    float ha = 0.f;
#pragma unroll
    for (int j = 0; j < 20; j++) ha += s[j] * mem[j][d];
    float hv = h[d][tid];
    HdT[(size_t)d * NB + r] = hv;
    HdT[(size_t)(64 + d) * NB + r] = ha;
    bf16 hb = __float2bfloat16(hv), ab = __float2bfloat16(ha);
    XTh[((size_t)b * 134 + d) * 512 + n] = hb;
    XTh[((size_t)b * 134 + 64 + d) * 512 + n] = ab;
    XCh[(size_t)r * 160 + d] = hb;
    XCh[(size_t)r * 160 + 64 + d] = ab;
  }
}

// ---------------- host ----------------
extern "C" void kernel_launch(void* const* d_in, const int* in_sizes, int n_in,
                              void* d_out, int out_size, void* d_ws, size_t ws_size,
                              hipStream_t stream) {
  const float* x   = (const float*)d_in[0];
  const float* tt  = (const float*)d_in[3];
  const float* Mem = (const float*)d_in[5];
  const float* Wq  = (const float*)d_in[6];
  const float* We1 = (const float*)d_in[7];
  const float* We2 = (const float*)d_in[8];
  const float* egW = (const float*)d_in[9];
  const float* egb = (const float*)d_in[10];
  const float* euW = (const float*)d_in[11];
  const float* eub = (const float*)d_in[12];
  const float* dgW = (const float*)d_in[13];
  const float* dgb = (const float*)d_in[14];
  const float* duW = (const float*)d_in[15];
  const float* dub = (const float*)d_in[16];
  const float* pW  = (const float*)d_in[17];
  const float* pb  = (const float*)d_in[18];
  float* out = (float*)d_out;

  char* ws = (char*)d_ws;
  size_t off = 0;
  auto alloc = [&](size_t bytes) { char* p = ws + off; off += (bytes + 255) & ~(size_t)255; return p; };
  // ---- zeroed-at-launch-start region ----
  bf16* XTh   = (bf16*)alloc((size_t)8576 * 512 * 2);
  bf16* XCh   = (bf16*)alloc((size_t)NB * 160 * 2);
  float* HbT  = (float*)alloc((size_t)RNN * NB * 4);
  size_t zero_bytes = off;
  // ---- rest ----
  bf16* XTz   = (bf16*)alloc((size_t)8576 * 512 * 2);
  bf16* XCz   = (bf16*)alloc((size_t)NB * 160 * 2);
  bf16* Ybuf  = (bf16*)alloc((size_t)4 * NB * 160 * 2);
  bf16* RG    = (bf16*)alloc((size_t)DD * NB * 2);
  bf16* WTeg  = (bf16*)alloc((size_t)5 * 128 * 96 * 2);
  bf16* WTeu  = (bf16*)alloc((size_t)5 * 64 * 96 * 2);
  bf16* WTdg  = (bf16*)alloc((size_t)5 * 256 * 160 * 2);
  bf16* WTdu  = (bf16*)alloc((size_t)5 * 128 * 160 * 2);
  bf16* Sb    = (bf16*)alloc((size_t)4 * 512 * 512 * 2);
  bf16* g1T   = (bf16*)alloc((size_t)512 * 512 * 2);
  bf16* g2T   = (bf16*)alloc((size_t)512 * 512 * 2);
  float* HdT  = (float*)alloc((size_t)DD * NB * 4);
  float* WqM  = (float*)alloc((size_t)RNN * MEMN * 4);
  float* e1   = (float*)alloc((size_t)N_ * MEMD * 4);
  float* e2   = (float*)alloc((size_t)N_ * MEMD * 4);
  float* S    = (float*)alloc((size_t)N_ * N_ * 4);
  float* ST   = (float*)alloc((size_t)N_ * N_ * 4);
  float* g1f  = (float*)alloc((size_t)N_ * N_ * 4);
  float* g2f  = (float*)alloc((size_t)N_ * N_ * 4);

  auto blk = [](long n) { return dim3((unsigned)((n + 255) / 256)); };

  // ---- phase 0 ----
  fill_zero4<<<2048, 256, 0, stream>>>((float4*)ws, (int)(zero_bytes / 16));
  compute_e<<<blk(N_ * MEMD), 256, 0, stream>>>(We1, We2, Mem, e1, e2);
  compute_wqm<<<blk(RNN * MEMN), 256, 0, stream>>>(Wq, Mem, WqM);
  scores_relu<<<blk(N_ * N_), 256, 0, stream>>>(e1, e2, S);
  trans_f32<<<dim3(16, 16), dim3(32, 8), 0, stream>>>(S, ST);
  row_softmax<<<N_, 256, 0, stream>>>(S, g1f);
  row_softmax<<<N_, 256, 0, stream>>>(ST, g2f);
  trans_to_bf16<<<dim3(16, 16), dim3(32, 8), 0, stream>>>(g1f, Sb + 0 * 262144, g1T);
  trans_to_bf16<<<dim3(16, 16), dim3(32, 8), 0, stream>>>(g2f, Sb + 2 * 262144, g2T);
  gemm_cheb<<<dim3(4, 4), 256, 0, stream>>>(Sb + 0 * 262144, g1T, Sb + 1 * 262144);
  gemm_cheb<<<dim3(4, 4), 256, 0, stream>>>(Sb + 2 * 262144, g2T, Sb + 3 * 262144);
  prep_wt<<<blk(5 * 128 * 96), 256, 0, stream>>>(egW, WTeg, 65, 128, 128, 96, 64, 1);
  prep_wt<<<blk(5 * 64 * 96), 256, 0, stream>>>(euW, WTeu, 65, 64, 64, 96, 64, 1);
  prep_wt<<<blk(5 * 256 * 160), 256, 0, stream>>>(dgW, WTdg, 134, 256, 256, 160, 128, 6);
  prep_wt<<<blk(5 * 128 * 160), 256, 0, stream>>>(duW, WTdu, 134, 128, 128, 160, 128, 6);

  // ---- encoder ----
  fill_misc_enc<<<blk(NB), 256, 0, stream>>>(XTh, XTz, XCh, XCz, x, 0);
  for (int t = 0; t < L_; t++) {
    gemm_mix<65, 96><<<dim3(33, 16), 256, 0, stream>>>(Sb, XTh, Ybuf);
    gemm_proj<96, 128, 0, 65><<<1024, 256, 0, stream>>>(
        WTeg, XCh, Ybuf, egb, RG, HbT, RNN, nullptr, nullptr, nullptr,
        XTz, XCz, nullptr, nullptr, 0, nullptr, 99);
    gemm_mix<65, 96><<<dim3(33, 16), 256, 0, stream>>>(Sb, XTz, Ybuf);
    gemm_proj<96, 64, 1, 65><<<1024, 256, 0, stream>>>(
        WTeu, XCz, Ybuf, eub, RG, HbT, RNN, nullptr, nullptr, nullptr,
        XTh, XCh, XTz, XCz, 0, x, t + 1);
  }

  // ---- attention -> HdT + seed dec gates input ----
  attention2<<<dim3(256), 128, 0, stream>>>(HbT, WqM, Mem, HdT, XTh, XCh);

  // ---- decoder ----
  fill_misc_dec<<<blk((long)NB * 6), 256, 0, stream>>>(XTh, XTz, XCh, XCz, tt, 0, 1);
  for (int t = 0; t < H_; t++) {
    gemm_mix<134, 160><<<dim3(67, 16), 256, 0, stream>>>(Sb, XTh, Ybuf);
    gemm_proj<160, 256, 0, 134><<<1024, 256, 0, stream>>>(
        WTdg, XCh, Ybuf, dgb, RG, HdT, DD, nullptr, nullptr, nullptr,
        XTz, XCz, nullptr, nullptr, 0, nullptr, 99);
    gemm_mix<134, 160><<<dim3(67, 16), 256, 0, stream>>>(Sb, XTz, Ybuf);
    gemm_proj<160, 128, 2, 134><<<1024, 256, 0, stream>>>(
        WTdu, XCz, Ybuf, dub, RG, HdT, DD, pW, pb, out,
        XTh, XCh, XTz, XCz, t, tt, t + 1);
  }
}